// Round 4
// baseline (667.419 us; speedup 1.0000x reference)
//
#include <hip/hip_runtime.h>
#include <cstdint>
#include <cstddef>

#define B_ 8
#define C_ 512
#define H_ 64
#define W_ 128
#define HW_ 8192
#define K_ 19
#define N_ 8
#define P_ 1024
#define CI_ 256

typedef unsigned short u16;
typedef unsigned int u32;
typedef __attribute__((ext_vector_type(8))) short bf16x8;   // 8 bf16 (4 VGPRs)
typedef __attribute__((ext_vector_type(4))) float f32x4;    // 4 fp32 acc

__device__ __forceinline__ u16 f2bf(float f) {
  u32 u = __float_as_uint(f);
  u32 r = (u + 0x7FFFu + ((u >> 16) & 1u)) >> 16;
  return (u16)r;
}
__device__ __forceinline__ float bf2f(u16 h) {
  return __uint_as_float(((u32)h) << 16);
}

// async global->LDS, 16B per lane; LDS dest is wave-uniform base + lane*16
__device__ __forceinline__ void gload16(const u16* g, u16* l) {
  __builtin_amdgcn_global_load_lds(
      (const __attribute__((address_space(1))) unsigned int*)g,
      (__attribute__((address_space(3))) unsigned int*)l, 16, 0, 0);
}

// ---- swizzled tile staging: rows of 64 u16 (128B), 16B-chunk XOR swizzle ----
__device__ __forceinline__ void stage128(const u16* __restrict__ src, size_t ld, int k0,
                                         u16* lds, int wave, int lane) {
  int rsub = lane >> 3;
  int swz = ((lane & 7) ^ rsub) << 3;
#pragma unroll
  for (int i = 0; i < 4; i++) {
    int rowbase = wave * 8 + i * 32;
    gload16(src + (size_t)(rowbase + rsub) * ld + k0 + swz, lds + rowbase * 64);
  }
}
__device__ __forceinline__ void stage32(const u16* __restrict__ src, size_t ld, int k0,
                                        u16* lds, int wave, int lane) {
  int rsub = lane >> 3;
  int swz = ((lane & 7) ^ rsub) << 3;
  int rowbase = wave * 8;
  gload16(src + (size_t)(rowbase + rsub) * ld + k0 + swz, lds + rowbase * 64);
}
__device__ __forceinline__ bf16x8 frag(const u16* lds, int row, int qbyte) {
  return *(const bf16x8*)((const char*)lds + row * 128 + (qbyte ^ ((row & 7) << 4)));
}

// ---------------- block reductions (256 threads = 4 waves) ----------------
__device__ __forceinline__ float blockSum256(float v, float* red4) {
#pragma unroll
  for (int o = 32; o > 0; o >>= 1) v += __shfl_down(v, o, 64);
  __syncthreads();
  if ((threadIdx.x & 63) == 0) red4[threadIdx.x >> 6] = v;
  __syncthreads();
  return red4[0] + red4[1] + red4[2] + red4[3];
}

__device__ __forceinline__ float blockMax256(float v, float* red4) {
#pragma unroll
  for (int o = 32; o > 0; o >>= 1) v = fmaxf(v, __shfl_down(v, o, 64));
  __syncthreads();
  if ((threadIdx.x & 63) == 0) red4[threadIdx.x >> 6] = v;
  __syncthreads();
  return fmaxf(fmaxf(red4[0], red4[1]), fmaxf(red4[2], red4[3]));
}

__device__ __forceinline__ void cvt4(const float* __restrict__ s, u16* __restrict__ d, int i) {
  float4 v = *(const float4*)&s[(size_t)i * 4];
  ushort4 o;
  o.x = f2bf(v.x); o.y = f2bf(v.y); o.z = f2bf(v.z); o.w = f2bf(v.w);
  *(ushort4*)&d[(size_t)i * 4] = o;
}

// ---------------- fused transpose + prologue ----------------
// blocks 0..8191: transpose; 8192..: prep (kw 128 | gw2 256 | camw 16 | sums 1 | tpad 16)
__global__ __launch_bounds__(256) void xpose_prep_kernel(const float* __restrict__ x,
                                                         u16* __restrict__ xt,
                                                         const float* __restrict__ kw,
                                                         const float* __restrict__ gw2,
                                                         const float* __restrict__ camw,
                                                         u16* __restrict__ kwbf,
                                                         u16* __restrict__ gw2bf,
                                                         u16* __restrict__ camwbf,
                                                         float* __restrict__ sums,
                                                         float* __restrict__ tpad) {
  __shared__ float tile[64][65];
  int bid = blockIdx.x;
  int tid = threadIdx.x;
  if (bid >= 8192) {
    int pb = bid - 8192;
    if (pb < 128) {
      cvt4(kw, kwbf, pb * 256 + tid);
    } else if (pb < 384) {
      cvt4(gw2, gw2bf, (pb - 128) * 256 + tid);
    } else if (pb < 400) {
      int i = (pb - 384) * 256 + tid;
      if (i * 4 < K_ * C_) {
        cvt4(camw, camwbf, i);
      } else {
        ushort4 z; z.x = 0; z.y = 0; z.z = 0; z.w = 0;
        *(ushort4*)&camwbf[(size_t)i * 4] = z;
      }
    } else if (pb == 400) {
      float4 z; z.x = 0.f; z.y = 0.f; z.z = 0.f; z.w = 0.f;
      *(float4*)&sums[tid * 4] = z;  // sums(512)+sumsq(512) contiguous
    } else {
      int i = (pb - 401) * 256 + tid;
      float4 z; z.x = 0.f; z.y = 0.f; z.z = 0.f; z.w = 0.f;
      *(float4*)&tpad[(size_t)i * 4] = z;
    }
    return;
  }
  int hw0 = (bid & 127) << 6;
  int c0 = ((bid >> 7) & 7) << 6;
  int b = bid >> 10;
  int r = tid >> 4;
  int col4 = (tid & 15) << 2;
  const float* xb = x + ((size_t)b * C_ + c0) * HW_ + hw0;
#pragma unroll
  for (int it = 0; it < 4; it++) {
    int rr = r + it * 16;
    float4 v = *(const float4*)&xb[(size_t)rr * HW_ + col4];
    tile[rr][col4 + 0] = v.x;
    tile[rr][col4 + 1] = v.y;
    tile[rr][col4 + 2] = v.z;
    tile[rr][col4 + 3] = v.w;
  }
  __syncthreads();
  u16* xo = xt + ((size_t)b * HW_ + hw0) * C_ + c0;
#pragma unroll
  for (int it = 0; it < 4; it++) {
    int hwr = r + it * 16;
    ushort4 o;
    o.x = f2bf(tile[col4 + 0][hwr]);
    o.y = f2bf(tile[col4 + 1][hwr]);
    o.z = f2bf(tile[col4 + 2][hwr]);
    o.w = f2bf(tile[col4 + 3][hwr]);
    *(ushort4*)&xo[(size_t)hwr * C_ + col4] = o;
  }
}

// ---------------- cam via MFMA: cam[b,k,hw] = xt[b,hw,:].camw[k,:] + camb[k] ----------------
__global__ __launch_bounds__(256) void gemm_cam_kernel(const u16* __restrict__ A,
                                                       const u16* __restrict__ Bw,
                                                       const float* __restrict__ bias,
                                                       float* __restrict__ cam) {
  __shared__ __align__(16) u16 As[128 * 64];
  __shared__ __align__(16) u16 Bs[32 * 64];
  int b = blockIdx.y;
  int m0 = blockIdx.x * 128;
  int tid = threadIdx.x;
  int wave = tid >> 6, lane = tid & 63;
  int wm = wave * 32;
  int quad = lane >> 4, l16 = lane & 15;
  const u16* Ab = A + (size_t)b * HW_ * C_ + (size_t)m0 * C_;
  f32x4 acc[2][2] = {};
  for (int k0 = 0; k0 < C_; k0 += 64) {
    __syncthreads();
    stage128(Ab, C_, k0, As, wave, lane);
    stage32(Bw, C_, k0, Bs, wave, lane);
    __syncthreads();
#pragma unroll
    for (int kk = 0; kk < 2; kk++) {
      int qb_ = kk * 64 + quad * 16;
      bf16x8 af[2], bfv[2];
#pragma unroll
      for (int t = 0; t < 2; t++) {
        af[t] = frag(As, wm + t * 16 + l16, qb_);
        bfv[t] = frag(Bs, t * 16 + l16, qb_);
      }
#pragma unroll
      for (int tm = 0; tm < 2; tm++)
#pragma unroll
        for (int tn = 0; tn < 2; tn++)
          acc[tm][tn] = __builtin_amdgcn_mfma_f32_16x16x32_bf16(af[tm], bfv[tn], acc[tm][tn], 0, 0, 0);
    }
  }
  float* C = cam + (size_t)b * K_ * HW_;
#pragma unroll
  for (int tm = 0; tm < 2; tm++) {
    int mm = m0 + wm + tm * 16 + quad * 4;
#pragma unroll
    for (int tn = 0; tn < 2; tn++) {
      int nn = tn * 16 + l16;
      if (nn < K_) {
        float bv = bias[nn];
        f32x4 v = acc[tm][tn];
        v[0] += bv; v[1] += bv; v[2] += bv; v[3] += bv;
        *(f32x4*)&C[(size_t)nn * HW_ + mm] = v;
      }
    }
  }
}

// ---------------- fused cls+softmax ----------------
__global__ __launch_bounds__(256) void softcls_kernel(const float* __restrict__ cam,
                                                      float* __restrict__ bconf,
                                                      float* __restrict__ pconf) {
  __shared__ float red4[4];
  int bid = blockIdx.x;
  int k = bid % 19;
  int n = (bid / 19) & 7;
  int b = bid / 152;
  int bh = n >> 2, bw = n & 3;
  const float* base = cam + ((size_t)b * K_ + k) * HW_ + (bh * 32) * W_ + bw * 32;
  float v[4];
  float s = 0.f, mx = -1e30f;
#pragma unroll
  for (int j = 0; j < 4; j++) {
    int p = threadIdx.x + j * 256;
    v[j] = base[(p >> 5) * W_ + (p & 31)];
    s += v[j];
    mx = fmaxf(mx, v[j]);
  }
  float tot = blockSum256(s, red4);
  if (threadIdx.x == 0) {
    float m = tot * (1.f / 1024.f);
    bconf[bid] = 1.f / (1.f + __expf(-m));
  }
  mx = blockMax256(mx, red4);
  float e[4];
  float se = 0.f;
#pragma unroll
  for (int j = 0; j < 4; j++) { e[j] = __expf(v[j] - mx); se += e[j]; }
  se = blockSum256(se, red4);
  float inv = 1.f / se;
  float* outp = pconf + (size_t)bid * P_;
#pragma unroll
  for (int j = 0; j < 4; j++) outp[threadIdx.x + j * 256] = e[j] * inv;
}

// ---------------- local partial: sum over 256-p chunk ----------------
__global__ __launch_bounds__(256) void local_part_kernel(const u16* __restrict__ xt,
                                                         const float* __restrict__ pconf,
                                                         float* __restrict__ part) {
  __shared__ __align__(16) float pcl[19 * 256];
  int bid = blockIdx.x;
  int pq = bid & 3;
  int half = (bid >> 2) & 1;
  int n = (bid >> 3) & 7;
  int b = bid >> 6;
  int tid = threadIdx.x;
  int c = half * 256 + tid;
  int bh = n >> 2, bw = n & 3;
  const float* pcb = pconf + (size_t)((b * N_ + n) * K_) * P_ + pq * 256;
  for (int e = tid; e < 19 * 64; e += 256) {
    int k = e >> 6, q4 = e & 63;
    *(float4*)&pcl[k * 256 + q4 * 4] = *(const float4*)&pcb[(size_t)k * P_ + q4 * 4];
  }
  __syncthreads();
  float acc[K_];
#pragma unroll
  for (int k = 0; k < K_; k++) acc[k] = 0.f;
  const u16* xb = xt + (size_t)b * HW_ * C_ + c;
  for (int pl0 = 0; pl0 < 256; pl0 += 8) {
    float xv[8];
#pragma unroll
    for (int g = 0; g < 2; g++) {
      int p = pq * 256 + pl0 + g * 4;
      int hw = (bh * 32 + (p >> 5)) * W_ + bw * 32 + (p & 31);
      const u16* xr = xb + (size_t)hw * C_;
#pragma unroll
      for (int j = 0; j < 4; j++) xv[g * 4 + j] = bf2f(xr[(size_t)j * C_]);
    }
#pragma unroll
    for (int k = 0; k < K_; k++) {
      float4 p0 = *(const float4*)&pcl[k * 256 + pl0];
      float4 p1 = *(const float4*)&pcl[k * 256 + pl0 + 4];
      acc[k] += p0.x * xv[0] + p0.y * xv[1] + p0.z * xv[2] + p0.w * xv[3]
              + p1.x * xv[4] + p1.y * xv[5] + p1.z * xv[6] + p1.w * xv[7];
    }
  }
  int row = (b * N_ + n) * K_;
  float* pp = part + ((size_t)pq * 1216 + row) * C_ + c;
#pragma unroll
  for (int k = 0; k < K_; k++) pp[(size_t)k * C_] = acc[k];
}

// ---------------- fused: local reduce + gcn conv + prelu -> bf16 ----------------
__global__ __launch_bounds__(256) void t_kernel(const float* __restrict__ part,
                                                const float* __restrict__ bconf,
                                                const float* __restrict__ gw1,
                                                const float* __restrict__ ga,
                                                u16* __restrict__ tbuf) {
  __shared__ float gw1l[64];
  __shared__ float gal[8];
  __shared__ float bcl[8];
  int tid = threadIdx.x;
  int bid = blockIdx.x;
  int half = bid & 1;
  int rem = bid >> 1;
  int k = rem % 19;
  int b = rem / 19;
  if (tid < 64) gw1l[tid] = gw1[tid];
  if (tid < 8) {
    gal[tid] = ga[tid];
    bcl[tid] = bconf[(size_t)(b * 8 + tid) * 19 + k];
  }
  __syncthreads();
  int c = half * 256 + tid;
  float lm[8];
#pragma unroll
  for (int m = 0; m < 8; m++) {
    size_t off = ((size_t)(b * N_ + m) * K_ + k) * C_ + c;
    lm[m] = (part[off] + part[off + (size_t)1216 * 512] +
             part[off + (size_t)2 * 1216 * 512] + part[off + (size_t)3 * 1216 * 512]) * bcl[m];
  }
#pragma unroll
  for (int n = 0; n < 8; n++) {
    float v = lm[n];
#pragma unroll
    for (int m = 0; m < 8; m++) v += gw1l[n * 8 + m] * lm[m];
    float t = fmaxf(v, 0.f) + gal[n] * fminf(v, 0.f);
    tbuf[((size_t)((b * N_ + n) * K_ + k)) * C_ + c] = f2bf(t);
  }
}

// ---------------- small GEMM body (M=1280 padded): C = A.Bw^T (+bias) --------
template <int KDIM, int NDIM, bool BIAS>
__device__ __forceinline__ void gemm_small_body(int bidx,
                                                const u16* __restrict__ A,
                                                const u16* __restrict__ Bw,
                                                const float* __restrict__ bias,
                                                float* __restrict__ f32out,
                                                u16* __restrict__ bf16out,
                                                u16* As, u16* Bs) {
  constexpr int NT = NDIM / 128;
  int m0 = (bidx / NT) * 128;
  int n0 = (bidx % NT) * 128;
  int tid = threadIdx.x;
  int wave = tid >> 6, lane = tid & 63;
  int wm = (wave >> 1) * 64, wn = (wave & 1) * 64;
  int quad = lane >> 4, l16 = lane & 15;
  const u16* Ab = A + (size_t)m0 * KDIM;
  const u16* Bb = Bw + (size_t)n0 * KDIM;
  f32x4 acc[4][4] = {};
  for (int k0 = 0; k0 < KDIM; k0 += 64) {
    __syncthreads();
    stage128(Ab, KDIM, k0, As, wave, lane);
    stage128(Bb, KDIM, k0, Bs, wave, lane);
    __syncthreads();
#pragma unroll
    for (int kk = 0; kk < 2; kk++) {
      int qb_ = kk * 64 + quad * 16;
      bf16x8 af[4], bfv[4];
#pragma unroll
      for (int t = 0; t < 4; t++) {
        af[t] = frag(As, wm + t * 16 + l16, qb_);
        bfv[t] = frag(Bs, wn + t * 16 + l16, qb_);
      }
#pragma unroll
      for (int tm = 0; tm < 4; tm++)
#pragma unroll
        for (int tn = 0; tn < 4; tn++)
          acc[tm][tn] = __builtin_amdgcn_mfma_f32_16x16x32_bf16(af[tm], bfv[tn], acc[tm][tn], 0, 0, 0);
    }
  }
  float bv[4];
#pragma unroll
  for (int tn = 0; tn < 4; tn++)
    bv[tn] = BIAS ? bias[n0 + wn + tn * 16 + l16] : 0.f;
#pragma unroll
  for (int tm = 0; tm < 4; tm++) {
    int mm = m0 + wm + tm * 16 + quad * 4;
#pragma unroll
    for (int tn = 0; tn < 4; tn++) {
      int nn = n0 + wn + tn * 16 + l16;
#pragma unroll
      for (int reg = 0; reg < 4; reg++) {
        float v = acc[tm][tn][reg] + bv[tn];
        if (f32out) f32out[(size_t)(mm + reg) * NDIM + nn] = v;
        if (bf16out) bf16out[(size_t)(mm + reg) * NDIM + nn] = f2bf(v);
      }
    }
  }
}

template <int KDIM, int NDIM, bool BIAS>
__global__ __launch_bounds__(256) void gemm_small_kernel(const u16* __restrict__ A,
                                                         const u16* __restrict__ Bw,
                                                         const float* __restrict__ bias,
                                                         float* __restrict__ f32out,
                                                         u16* __restrict__ bf16out) {
  __shared__ __align__(16) u16 As[128 * 64];
  __shared__ __align__(16) u16 Bs[128 * 64];
  gemm_small_body<KDIM, NDIM, BIAS>(blockIdx.x, A, Bw, bias, f32out, bf16out, As, Bs);
}

// ---------------- glob + val body ----------------
__device__ __forceinline__ void glob_val_body(int bid,
                                              const float* __restrict__ locl2,
                                              const float* __restrict__ fw,
                                              const float* __restrict__ fb,
                                              const float* __restrict__ ra,
                                              const float* __restrict__ vw,
                                              const float* __restrict__ vb,
                                              float* __restrict__ valo,
                                              float* gl) {
  int k = bid % 19;
  int b = bid / 19;
  int tid = threadIdx.x;
  float fwr[8];
#pragma unroll
  for (int m = 0; m < 8; m++) fwr[m] = fw[m];
  float fbv = fb[0], rav = ra[0];
  const float* lb = locl2 + ((size_t)(b * N_) * K_ + k) * C_;
  for (int c = tid; c < C_; c += 256) {
    float v = fbv;
#pragma unroll
    for (int m = 0; m < 8; m++) v += fwr[m] * lb[(size_t)m * K_ * C_ + c];
    gl[c] = fmaxf(v, 0.f) + rav * fminf(v, 0.f);
  }
  __syncthreads();
  int i = tid;
  const float* wr = vw + (size_t)i * C_;
  float s = vb[i];
  for (int c4 = 0; c4 < C_; c4 += 4) {
    float4 wv = *(const float4*)&wr[c4];
    float4 tv = *(const float4*)&gl[c4];
    s += wv.x * tv.x + wv.y * tv.y + wv.z * tv.z + wv.w * tv.w;
  }
  valo[(size_t)bid * CI_ + i] = s;
}

// merged: blocks 0..19 = key-projection small GEMM; blocks 20..171 = glob_val
__global__ __launch_bounds__(256) void small2_globval_kernel(const u16* __restrict__ A,
                                                             const u16* __restrict__ Bw,
                                                             const float* __restrict__ bias,
                                                             float* __restrict__ keyo,
                                                             const float* __restrict__ locl2,
                                                             const float* __restrict__ fw,
                                                             const float* __restrict__ fb,
                                                             const float* __restrict__ ra,
                                                             const float* __restrict__ vw,
                                                             const float* __restrict__ vb,
                                                             float* __restrict__ valo) {
  __shared__ __align__(16) u16 As[128 * 64];
  __shared__ __align__(16) u16 Bs[128 * 64];
  if (blockIdx.x < 20) {
    gemm_small_body<512, 256, true>(blockIdx.x, A, Bw, bias, keyo, nullptr, As, Bs);
  } else {
    glob_val_body(blockIdx.x - 20, locl2, fw, fb, ra, vw, vb, valo, (float*)As);
  }
}

// ---------------- QK2 / sbias / VO precompute ----------------
// blocks 0..63: per (b,n): QK2[k,c] = sum_i qw[i,c]*key[k,i] -> bf16 [32 pad][512]; sbias[k]=qb.key[k]
// blocks 64..71: per b: VO[k,c] = sum_i valo[k,i]*ow[c,i] (fp32)
__global__ __launch_bounds__(256) void qk2vo_kernel(const float* __restrict__ keyo,
                                                    const float* __restrict__ qw,
                                                    const float* __restrict__ qb,
                                                    const float* __restrict__ valo,
                                                    const float* __restrict__ ow,
                                                    u16* __restrict__ qk2bf,
                                                    float* __restrict__ sbias,
                                                    float* __restrict__ vo) {
  __shared__ float kl[19 * 256];
  int bid = blockIdx.x, tid = threadIdx.x;
  if (bid < 64) {
    const float* ks = keyo + (size_t)bid * 19 * 256;
    for (int e = tid; e < 19 * 256; e += 256) kl[e] = ks[e];
    __syncthreads();
    if (tid < 19) {
      float s = 0.f;
      for (int i = 0; i < 256; i++) s += qb[i] * kl[tid * 256 + i];
      sbias[(size_t)bid * 19 + tid] = s;
    }
    float a0[19], a1[19];
#pragma unroll
    for (int k = 0; k < 19; k++) { a0[k] = 0.f; a1[k] = 0.f; }
    for (int i = 0; i < 256; i++) {
      float q0 = qw[(size_t)i * 512 + tid];
      float q1 = qw[(size_t)i * 512 + 256 + tid];
#pragma unroll
      for (int k = 0; k < 19; k++) {
        float kv = kl[k * 256 + i];
        a0[k] += q0 * kv;
        a1[k] += q1 * kv;
      }
    }
    u16* qo = qk2bf + (size_t)bid * 32 * 512;
#pragma unroll
    for (int k = 0; k < 19; k++) {
      qo[k * 512 + tid] = f2bf(a0[k]);
      qo[k * 512 + 256 + tid] = f2bf(a1[k]);
    }
  } else {
    int b = bid - 64;
    const float* vs = valo + (size_t)b * 19 * 256;
    for (int e = tid; e < 19 * 256; e += 256) kl[e] = vs[e];
    __syncthreads();
    float a0[19], a1[19];
#pragma unroll
    for (int k = 0; k < 19; k++) { a0[k] = 0.f; a1[k] = 0.f; }
    for (int i = 0; i < 256; i++) {
      float w0 = ow[(size_t)tid * 256 + i];
      float w1 = ow[(size_t)(tid + 256) * 256 + i];
#pragma unroll
      for (int k = 0; k < 19; k++) {
        float kv = kl[k * 256 + i];
        a0[k] += w0 * kv;
        a1[k] += w1 * kv;
      }
    }
    float* vob = vo + (size_t)b * 19 * 512;
#pragma unroll
    for (int k = 0; k < 19; k++) {
      vob[k * 512 + tid] = a0[k];
      vob[k * 512 + 256 + tid] = a1[k];
    }
  }
}

// ---------------- attention: MFMA scores + softmax + aff + BN stats ----------------
// grid 512: mt = bid&7 (128-px m-tile), n = (bid>>3)&7, b = bid>>6
__global__ __launch_bounds__(256) void attn3_kernel(const u16* __restrict__ xt,
                                                    const u16* __restrict__ qk2bf,
                                                    const float* __restrict__ sbias,
                                                    const float* __restrict__ vo,
                                                    float* __restrict__ aff,
                                                    float* __restrict__ sums,
                                                    float* __restrict__ sumsq) {
  __shared__ __align__(16) u16 As[128 * 64];
  __shared__ __align__(16) u16 Bs[32 * 64];
  __shared__ __align__(16) float aff_l[128][24];
  int bid = blockIdx.x;
  int mt = bid & 7, n = (bid >> 3) & 7, b = bid >> 6;
  int bh = n >> 2, bw = n & 3;
  int tid = threadIdx.x;
  int wave = tid >> 6, lane = tid & 63;
  int wm = wave * 32;
  int quad = lane >> 4, l16 = lane & 15;
  int hwbase = bh * 4096 + bw * 32 + mt * 512;  // mt*4 rows * 128
  const u16* Ab = xt + ((size_t)b * HW_ + hwbase) * C_;
  const u16* Bb = qk2bf + (size_t)(b * 8 + n) * 32 * 512;
  f32x4 acc[2][2] = {};
  int rsub = lane >> 3;
  int swz = ((lane & 7) ^ rsub) << 3;
  for (int k0 = 0; k0 < C_; k0 += 64) {
    __syncthreads();
#pragma unroll
    for (int i = 0; i < 4; i++) {
      int rb = wave * 8 + i * 32;
      int r = rb + rsub;
      gload16(Ab + (size_t)((r >> 5) * 128 + (r & 31)) * C_ + k0 + swz, As + rb * 64);
    }
    stage32(Bb, 512, k0, Bs, wave, lane);
    __syncthreads();
#pragma unroll
    for (int kk = 0; kk < 2; kk++) {
      int qb_ = kk * 64 + quad * 16;
      bf16x8 af2[2], bfv[2];
#pragma unroll
      for (int t = 0; t < 2; t++) {
        af2[t] = frag(As, wm + t * 16 + l16, qb_);
        bfv[t] = frag(Bs, t * 16 + l16, qb_);
      }
#pragma unroll
      for (int tm = 0; tm < 2; tm++)
#pragma unroll
        for (int tn = 0; tn < 2; tn++)
          acc[tm][tn] = __builtin_amdgcn_mfma_f32_16x16x32_bf16(af2[tm], bfv[tn], acc[tm][tn], 0, 0, 0);
    }
  }
  // softmax over k (19 classes spread across l16 in 2 n-tiles)
  const float* sb = sbias + (size_t)(b * 8 + n) * 19;
  float sb0 = sb[l16];
  float sb1 = (l16 < 3) ? sb[16 + l16] : 0.f;
#pragma unroll
  for (int tm = 0; tm < 2; tm++)
#pragma unroll
    for (int reg = 0; reg < 4; reg++) {
      float v0 = acc[tm][0][reg] + sb0;
      float v1 = (l16 < 3) ? (acc[tm][1][reg] + sb1) : -1e30f;
      float mx = fmaxf(v0, v1);
#pragma unroll
      for (int o = 8; o > 0; o >>= 1) mx = fmaxf(mx, __shfl_xor(mx, o, 16));
      float e0 = __expf(v0 - mx);
      float e1 = (l16 < 3) ? __expf(v1 - mx) : 0.f;
      float s = e0 + e1;
#pragma unroll
      for (int o = 8; o > 0; o >>= 1) s += __shfl_xor(s, o, 16);
      float inv = 1.f / s;
      int rl = wm + tm * 16 + quad * 4 + reg;
      aff_l[rl][l16] = e0 * inv;
      if (l16 < 3) aff_l[rl][16 + l16] = e1 * inv;
    }
  __syncthreads();
  // write aff (fp32) [bin][k][1024 px]
  float* ab = aff + ((size_t)(b * 8 + n) * 19) * 1024 + mt * 128;
  for (int e = tid; e < 19 * 128; e += 256) {
    int k = e >> 7, px = e & 127;
    ab[(size_t)k * 1024 + px] = aff_l[px][k];
  }
  // BN stats: y = aff . VO for this block's 128 px, all 512 c
  const float* vob = vo + (size_t)b * 19 * 512;
  float v0r[19], v1r[19];
#pragma unroll
  for (int k = 0; k < 19; k++) {
    v0r[k] = vob[k * 512 + tid];
    v1r[k] = vob[k * 512 + 256 + tid];
  }
  float s0 = 0.f, q0 = 0.f, s1 = 0.f, q1 = 0.f;
  for (int px = 0; px < 128; px++) {
    const float4* ar4 = (const float4*)aff_l[px];
    float4 a0 = ar4[0], a1 = ar4[1], a2 = ar4[2], a3 = ar4[3], a4 = ar4[4];
    float y0 = a0.x * v0r[0] + a0.y * v0r[1] + a0.z * v0r[2] + a0.w * v0r[3]
             + a1.x * v0r[4] + a1.y * v0r[5] + a1.z * v0r[6] + a1.w * v0r[7]
             + a2.x * v0r[8] + a2.y * v0r[9] + a2.z * v0r[10] + a2.w * v0r[11]
             + a3.x * v0r[12] + a3.y * v0r[13] + a3.z * v0r[14] + a3.w * v0r[15]
             + a4.x * v0r[16] + a4.y * v0r[17] + a4.z * v0r[18];
    float y1 = a0.x * v1r[0] + a0.y * v1r[1] + a0.z * v1r[2] + a0.w * v1r[3]
             + a1.x * v1r[4] + a1.y * v1r[5] + a1.z * v1r[6] + a1.w * v1r[7]
             + a2.x * v1r[8] + a2.y * v1r[9] + a2.z * v1r[10] + a2.w * v1r[11]
             + a3.x * v1r[12] + a3.y * v1r[13] + a3.z * v1r[14] + a3.w * v1r[15]
             + a4.x * v1r[16] + a4.y * v1r[17] + a4.z * v1r[18];
    s0 += y0; q0 += y0 * y0;
    s1 += y1; q1 += y1 * y1;
  }
  atomicAdd(&sums[tid], s0);
  atomicAdd(&sumsq[tid], q0);
  atomicAdd(&sums[256 + tid], s1);
  atomicAdd(&sumsq[256 + tid], q1);
}

// ---------------- final: y = aff.VO, BN(inline) + PReLU + residual ----------------
// grid 512: chunk = bid&63 (128 px), b = bid>>6; 256 thr = 128 px x 2 c-halves
__global__ __launch_bounds__(256) void final_kernel(const float* __restrict__ x,
                                                    const float* __restrict__ aff,
                                                    const float* __restrict__ vo,
                                                    const float* __restrict__ sums,
                                                    const float* __restrict__ sumsq,
                                                    const float* __restrict__ gamma,
                                                    const float* __restrict__ beta,
                                                    const float* __restrict__ oa,
                                                    float* __restrict__ out) {
  int bid = blockIdx.x;
  int chunk = bid & 63, b = bid >> 6;
  int tid = threadIdx.x;
  int pxl = tid & 127;
  int chalf = tid >> 7;
  int hw = chunk * 128 + pxl;
  int h = hw >> 7, w = hw & 127;
  int n = (h >> 5) * 4 + (w >> 5);
  int p = ((h & 31) << 5) + (w & 31);
  const float* ab = aff + ((size_t)(b * 8 + n) * 19) * 1024 + p;
  float af[19];
#pragma unroll
  for (int k = 0; k < 19; k++) af[k] = ab[(size_t)k * 1024];
  const float* vob = vo + (size_t)b * 19 * 512;
  const float inv_cnt = 1.f / 65536.f;
  size_t base = (size_t)b * C_ * HW_ + hw;
  int c0 = chalf * 256;
  for (int c = c0; c < c0 + 256; c++) {
    float y = 0.f;
#pragma unroll
    for (int k = 0; k < 19; k++) y += af[k] * vob[k * 512 + c];
    float mu = sums[c] * inv_cnt;
    float var = sumsq[c] * inv_cnt - mu * mu;
    float iv = rsqrtf(var + 1e-5f);
    float sc = gamma[c] * iv;
    float sh = beta[c] - mu * sc;
    float t = y * sc + sh;
    float pr = fmaxf(t, 0.f) + oa[c] * fminf(t, 0.f);
    size_t o = base + (size_t)c * HW_;
    out[o] = x[o] + pr;
  }
}

extern "C" void kernel_launch(void* const* d_in, const int* in_sizes, int n_in,
                              void* d_out, int out_size, void* d_ws, size_t ws_size,
                              hipStream_t stream) {
  const float* x     = (const float*)d_in[0];
  const float* camw  = (const float*)d_in[1];
  const float* camb  = (const float*)d_in[2];
  const float* gw1   = (const float*)d_in[3];
  const float* ga    = (const float*)d_in[4];
  const float* gw2   = (const float*)d_in[5];
  const float* fw    = (const float*)d_in[6];
  const float* fb    = (const float*)d_in[7];
  const float* ra    = (const float*)d_in[8];
  const float* qw    = (const float*)d_in[9];
  const float* qb    = (const float*)d_in[10];
  const float* kw    = (const float*)d_in[11];
  const float* kb    = (const float*)d_in[12];
  const float* vw    = (const float*)d_in[13];
  const float* vb    = (const float*)d_in[14];
  const float* ow    = (const float*)d_in[15];
  const float* gamma = (const float*)d_in[16];
  const float* beta  = (const float*)d_in[17];
  const float* oa    = (const float*)d_in[18];
  float* out = (float*)d_out;
  float* ws = (float*)d_ws;

  // ---- workspace layout (float units) ----
  float* cam    = ws;                          // 1,245,184
  float* bconf  = cam + 1245184;               // 2,048
  float* pconf  = bconf + 2048;                // 1,245,184
  float* aff    = pconf + 1245184;             // 1,245,184
  float* locl2f = aff + 1245184;               // 655,360
  float* keyo   = locl2f + 655360;             // 327,680
  float* valo   = keyo + 327680;               // 38,912
  float* sums   = valo + 38912;                // 512
  float* sumsq  = sums + 512;                  // 512
  float* sbias  = sumsq + 512;                 // 1,216
  float* vo     = sbias + 1216;                // 77,824
  float* part   = vo + 77824;                  // 2,490,368
  u16* kwbf   = (u16*)(part + 2490368);        // 131,072
  u16* gw2bf  = kwbf + 131072;                 // 262,144
  u16* camwbf = gw2bf + 262144;                // 16,384
  u16* tbuf   = camwbf + 16384;                // 655,360 (1280x512, rows 1216+ zeroed)
  u16* l2bf   = tbuf + 655360;                 // 655,360
  u16* qk2bf  = l2bf + 655360;                 // 1,048,576 (64 bins x 32 x 512)
  u16* xt     = qk2bf + 1048576;               // 33,554,432 (64 MB)

  xpose_prep_kernel<<<8609, 256, 0, stream>>>(x, xt, kw, gw2, camw,
                                              kwbf, gw2bf, camwbf,
                                              sums, (float*)(tbuf + 1216 * 512));
  gemm_cam_kernel<<<dim3(64, 8), 256, 0, stream>>>(xt, camwbf, camb, cam);
  softcls_kernel<<<1216, 256, 0, stream>>>(cam, bconf, pconf);
  local_part_kernel<<<512, 256, 0, stream>>>(xt, pconf, part);
  t_kernel<<<304, 256, 0, stream>>>(part, bconf, gw1, ga, tbuf);
  gemm_small_kernel<512, 512, false>
      <<<40, 256, 0, stream>>>(tbuf, gw2bf, nullptr, locl2f, l2bf);
  small2_globval_kernel<<<172, 256, 0, stream>>>(l2bf, kwbf, kb, keyo,
                                                 locl2f, fw, fb, ra, vw, vb, valo);
  qk2vo_kernel<<<72, 256, 0, stream>>>(keyo, qw, qb, valo, ow, qk2bf, sbias, vo);
  attn3_kernel<<<512, 256, 0, stream>>>(xt, qk2bf, sbias, vo, aff, sums, sumsq);
  final_kernel<<<512, 256, 0, stream>>>(x, aff, vo, sums, sumsq, gamma, beta, oa, out);
}

// Round 6
// 569.232 us; speedup vs baseline: 1.1725x; 1.1725x over previous
//
#include <hip/hip_runtime.h>
#include <cstdint>
#include <cstddef>

#define B_ 8
#define C_ 512
#define H_ 64
#define W_ 128
#define HW_ 8192
#define K_ 19
#define N_ 8
#define P_ 1024
#define CI_ 256

typedef unsigned short u16;
typedef unsigned int u32;
typedef __attribute__((ext_vector_type(8))) short bf16x8;   // 8 bf16 (4 VGPRs)
typedef __attribute__((ext_vector_type(4))) float f32x4;    // 4 fp32 acc

__device__ __forceinline__ u16 f2bf(float f) {
  u32 u = __float_as_uint(f);
  u32 r = (u + 0x7FFFu + ((u >> 16) & 1u)) >> 16;
  return (u16)r;
}
__device__ __forceinline__ float bf2f(u16 h) {
  return __uint_as_float(((u32)h) << 16);
}

// async global->LDS, 16B per lane; LDS dest is wave-uniform base + lane*16
__device__ __forceinline__ void gload16(const u16* g, u16* l) {
  __builtin_amdgcn_global_load_lds(
      (const __attribute__((address_space(1))) unsigned int*)g,
      (__attribute__((address_space(3))) unsigned int*)l, 16, 0, 0);
}

// ---- swizzled tile staging: rows of 64 u16 (128B), 16B-chunk XOR swizzle ----
__device__ __forceinline__ void stage128(const u16* __restrict__ src, size_t ld, int k0,
                                         u16* lds, int wave, int lane) {
  int rsub = lane >> 3;
  int swz = ((lane & 7) ^ rsub) << 3;
#pragma unroll
  for (int i = 0; i < 4; i++) {
    int rowbase = wave * 8 + i * 32;
    gload16(src + (size_t)(rowbase + rsub) * ld + k0 + swz, lds + rowbase * 64);
  }
}
__device__ __forceinline__ void stage32(const u16* __restrict__ src, size_t ld, int k0,
                                        u16* lds, int wave, int lane) {
  int rsub = lane >> 3;
  int swz = ((lane & 7) ^ rsub) << 3;
  int rowbase = wave * 8;
  gload16(src + (size_t)(rowbase + rsub) * ld + k0 + swz, lds + rowbase * 64);
}
__device__ __forceinline__ bf16x8 frag(const u16* lds, int row, int qbyte) {
  return *(const bf16x8*)((const char*)lds + row * 128 + (qbyte ^ ((row & 7) << 4)));
}

// ---------------- block reductions (256 threads = 4 waves) ----------------
__device__ __forceinline__ float blockSum256(float v, float* red4) {
#pragma unroll
  for (int o = 32; o > 0; o >>= 1) v += __shfl_down(v, o, 64);
  __syncthreads();
  if ((threadIdx.x & 63) == 0) red4[threadIdx.x >> 6] = v;
  __syncthreads();
  return red4[0] + red4[1] + red4[2] + red4[3];
}

__device__ __forceinline__ float blockMax256(float v, float* red4) {
#pragma unroll
  for (int o = 32; o > 0; o >>= 1) v = fmaxf(v, __shfl_down(v, o, 64));
  __syncthreads();
  if ((threadIdx.x & 63) == 0) red4[threadIdx.x >> 6] = v;
  __syncthreads();
  return fmaxf(fmaxf(red4[0], red4[1]), fmaxf(red4[2], red4[3]));
}

__device__ __forceinline__ void cvt4(const float* __restrict__ s, u16* __restrict__ d, int i) {
  float4 v = *(const float4*)&s[(size_t)i * 4];
  ushort4 o;
  o.x = f2bf(v.x); o.y = f2bf(v.y); o.z = f2bf(v.z); o.w = f2bf(v.w);
  *(ushort4*)&d[(size_t)i * 4] = o;
}

// ---------------- fused transpose + prologue ----------------
// blocks 0..8191: transpose; 8192..: prep (kw 128 | gw2 256 | camw 16 | sums 1 | tpad 16)
__global__ __launch_bounds__(256) void xpose_prep_kernel(const float* __restrict__ x,
                                                         u16* __restrict__ xt,
                                                         const float* __restrict__ kw,
                                                         const float* __restrict__ gw2,
                                                         const float* __restrict__ camw,
                                                         u16* __restrict__ kwbf,
                                                         u16* __restrict__ gw2bf,
                                                         u16* __restrict__ camwbf,
                                                         float* __restrict__ sums,
                                                         float* __restrict__ tpad) {
  __shared__ float tile[64][65];
  int bid = blockIdx.x;
  int tid = threadIdx.x;
  if (bid >= 8192) {
    int pb = bid - 8192;
    if (pb < 128) {
      cvt4(kw, kwbf, pb * 256 + tid);
    } else if (pb < 384) {
      cvt4(gw2, gw2bf, (pb - 128) * 256 + tid);
    } else if (pb < 400) {
      int i = (pb - 384) * 256 + tid;
      if (i * 4 < K_ * C_) {
        cvt4(camw, camwbf, i);
      } else {
        ushort4 z; z.x = 0; z.y = 0; z.z = 0; z.w = 0;
        *(ushort4*)&camwbf[(size_t)i * 4] = z;
      }
    } else if (pb == 400) {
      float4 z; z.x = 0.f; z.y = 0.f; z.z = 0.f; z.w = 0.f;
      *(float4*)&sums[tid * 4] = z;  // sums(512)+sumsq(512) contiguous
    } else {
      int i = (pb - 401) * 256 + tid;
      float4 z; z.x = 0.f; z.y = 0.f; z.z = 0.f; z.w = 0.f;
      *(float4*)&tpad[(size_t)i * 4] = z;
    }
    return;
  }
  int hw0 = (bid & 127) << 6;
  int c0 = ((bid >> 7) & 7) << 6;
  int b = bid >> 10;
  int r = tid >> 4;
  int col4 = (tid & 15) << 2;
  const float* xb = x + ((size_t)b * C_ + c0) * HW_ + hw0;
#pragma unroll
  for (int it = 0; it < 4; it++) {
    int rr = r + it * 16;
    float4 v = *(const float4*)&xb[(size_t)rr * HW_ + col4];
    tile[rr][col4 + 0] = v.x;
    tile[rr][col4 + 1] = v.y;
    tile[rr][col4 + 2] = v.z;
    tile[rr][col4 + 3] = v.w;
  }
  __syncthreads();
  u16* xo = xt + ((size_t)b * HW_ + hw0) * C_ + c0;
#pragma unroll
  for (int it = 0; it < 4; it++) {
    int hwr = r + it * 16;
    ushort4 o;
    o.x = f2bf(tile[col4 + 0][hwr]);
    o.y = f2bf(tile[col4 + 1][hwr]);
    o.z = f2bf(tile[col4 + 2][hwr]);
    o.w = f2bf(tile[col4 + 3][hwr]);
    *(ushort4*)&xo[(size_t)hwr * C_ + col4] = o;
  }
}

// ---------------- cam via MFMA: cam[b,k,hw] = xt[b,hw,:].camw[k,:] + camb[k] ----------------
__global__ __launch_bounds__(256) void gemm_cam_kernel(const u16* __restrict__ A,
                                                       const u16* __restrict__ Bw,
                                                       const float* __restrict__ bias,
                                                       float* __restrict__ cam) {
  __shared__ __align__(16) u16 As[128 * 64];
  __shared__ __align__(16) u16 Bs[32 * 64];
  int b = blockIdx.y;
  int m0 = blockIdx.x * 128;
  int tid = threadIdx.x;
  int wave = tid >> 6, lane = tid & 63;
  int wm = wave * 32;
  int quad = lane >> 4, l16 = lane & 15;
  const u16* Ab = A + (size_t)b * HW_ * C_ + (size_t)m0 * C_;
  f32x4 acc[2][2] = {};
  for (int k0 = 0; k0 < C_; k0 += 64) {
    __syncthreads();
    stage128(Ab, C_, k0, As, wave, lane);
    stage32(Bw, C_, k0, Bs, wave, lane);
    __syncthreads();
#pragma unroll
    for (int kk = 0; kk < 2; kk++) {
      int qb_ = kk * 64 + quad * 16;
      bf16x8 af[2], bfv[2];
#pragma unroll
      for (int t = 0; t < 2; t++) {
        af[t] = frag(As, wm + t * 16 + l16, qb_);
        bfv[t] = frag(Bs, t * 16 + l16, qb_);
      }
#pragma unroll
      for (int tm = 0; tm < 2; tm++)
#pragma unroll
        for (int tn = 0; tn < 2; tn++)
          acc[tm][tn] = __builtin_amdgcn_mfma_f32_16x16x32_bf16(af[tm], bfv[tn], acc[tm][tn], 0, 0, 0);
    }
  }
  float* C = cam + (size_t)b * K_ * HW_;
#pragma unroll
  for (int tm = 0; tm < 2; tm++) {
    int mm = m0 + wm + tm * 16 + quad * 4;
#pragma unroll
    for (int tn = 0; tn < 2; tn++) {
      int nn = tn * 16 + l16;
      if (nn < K_) {
        float bv = bias[nn];
        f32x4 v = acc[tm][tn];
        v[0] += bv; v[1] += bv; v[2] += bv; v[3] += bv;
        *(f32x4*)&C[(size_t)nn * HW_ + mm] = v;
      }
    }
  }
}

// ---------------- fused cls+softmax ----------------
__global__ __launch_bounds__(256) void softcls_kernel(const float* __restrict__ cam,
                                                      float* __restrict__ bconf,
                                                      float* __restrict__ pconf) {
  __shared__ float red4[4];
  int bid = blockIdx.x;
  int k = bid % 19;
  int n = (bid / 19) & 7;
  int b = bid / 152;
  int bh = n >> 2, bw = n & 3;
  const float* base = cam + ((size_t)b * K_ + k) * HW_ + (bh * 32) * W_ + bw * 32;
  float v[4];
  float s = 0.f, mx = -1e30f;
#pragma unroll
  for (int j = 0; j < 4; j++) {
    int p = threadIdx.x + j * 256;
    v[j] = base[(p >> 5) * W_ + (p & 31)];
    s += v[j];
    mx = fmaxf(mx, v[j]);
  }
  float tot = blockSum256(s, red4);
  if (threadIdx.x == 0) {
    float m = tot * (1.f / 1024.f);
    bconf[bid] = 1.f / (1.f + __expf(-m));
  }
  mx = blockMax256(mx, red4);
  float e[4];
  float se = 0.f;
#pragma unroll
  for (int j = 0; j < 4; j++) { e[j] = __expf(v[j] - mx); se += e[j]; }
  se = blockSum256(se, red4);
  float inv = 1.f / se;
  float* outp = pconf + (size_t)bid * P_;
#pragma unroll
  for (int j = 0; j < 4; j++) outp[threadIdx.x + j * 256] = e[j] * inv;
}

// ---------------- local partial: sum over 256-p chunk ----------------
__global__ __launch_bounds__(256) void local_part_kernel(const u16* __restrict__ xt,
                                                         const float* __restrict__ pconf,
                                                         float* __restrict__ part) {
  __shared__ __align__(16) float pcl[19 * 256];
  int bid = blockIdx.x;
  int pq = bid & 3;
  int half = (bid >> 2) & 1;
  int n = (bid >> 3) & 7;
  int b = bid >> 6;
  int tid = threadIdx.x;
  int c = half * 256 + tid;
  int bh = n >> 2, bw = n & 3;
  const float* pcb = pconf + (size_t)((b * N_ + n) * K_) * P_ + pq * 256;
  for (int e = tid; e < 19 * 64; e += 256) {
    int k = e >> 6, q4 = e & 63;
    *(float4*)&pcl[k * 256 + q4 * 4] = *(const float4*)&pcb[(size_t)k * P_ + q4 * 4];
  }
  __syncthreads();
  float acc[K_];
#pragma unroll
  for (int k = 0; k < K_; k++) acc[k] = 0.f;
  const u16* xb = xt + (size_t)b * HW_ * C_ + c;
  for (int pl0 = 0; pl0 < 256; pl0 += 8) {
    float xv[8];
#pragma unroll
    for (int g = 0; g < 2; g++) {
      int p = pq * 256 + pl0 + g * 4;
      int hw = (bh * 32 + (p >> 5)) * W_ + bw * 32 + (p & 31);
      const u16* xr = xb + (size_t)hw * C_;
#pragma unroll
      for (int j = 0; j < 4; j++) xv[g * 4 + j] = bf2f(xr[(size_t)j * C_]);
    }
#pragma unroll
    for (int k = 0; k < K_; k++) {
      float4 p0 = *(const float4*)&pcl[k * 256 + pl0];
      float4 p1 = *(const float4*)&pcl[k * 256 + pl0 + 4];
      acc[k] += p0.x * xv[0] + p0.y * xv[1] + p0.z * xv[2] + p0.w * xv[3]
              + p1.x * xv[4] + p1.y * xv[5] + p1.z * xv[6] + p1.w * xv[7];
    }
  }
  int row = (b * N_ + n) * K_;
  float* pp = part + ((size_t)pq * 1216 + row) * C_ + c;
#pragma unroll
  for (int k = 0; k < K_; k++) pp[(size_t)k * C_] = acc[k];
}

// ---------------- fused: local reduce + gcn conv + prelu -> bf16 ----------------
__global__ __launch_bounds__(256) void t_kernel(const float* __restrict__ part,
                                                const float* __restrict__ bconf,
                                                const float* __restrict__ gw1,
                                                const float* __restrict__ ga,
                                                u16* __restrict__ tbuf) {
  __shared__ float gw1l[64];
  __shared__ float gal[8];
  __shared__ float bcl[8];
  int tid = threadIdx.x;
  int bid = blockIdx.x;
  int half = bid & 1;
  int rem = bid >> 1;
  int k = rem % 19;
  int b = rem / 19;
  if (tid < 64) gw1l[tid] = gw1[tid];
  if (tid < 8) {
    gal[tid] = ga[tid];
    bcl[tid] = bconf[(size_t)(b * 8 + tid) * 19 + k];
  }
  __syncthreads();
  int c = half * 256 + tid;
  float lm[8];
#pragma unroll
  for (int m = 0; m < 8; m++) {
    size_t off = ((size_t)(b * N_ + m) * K_ + k) * C_ + c;
    lm[m] = (part[off] + part[off + (size_t)1216 * 512] +
             part[off + (size_t)2 * 1216 * 512] + part[off + (size_t)3 * 1216 * 512]) * bcl[m];
  }
#pragma unroll
  for (int n = 0; n < 8; n++) {
    float v = lm[n];
#pragma unroll
    for (int m = 0; m < 8; m++) v += gw1l[n * 8 + m] * lm[m];
    float t = fmaxf(v, 0.f) + gal[n] * fminf(v, 0.f);
    tbuf[((size_t)((b * N_ + n) * K_ + k)) * C_ + c] = f2bf(t);
  }
}

// ---------------- small GEMM body (M=1280 padded): C = A.Bw^T (+bias) --------
template <int KDIM, int NDIM, bool BIAS>
__device__ __forceinline__ void gemm_small_body(int bidx,
                                                const u16* __restrict__ A,
                                                const u16* __restrict__ Bw,
                                                const float* __restrict__ bias,
                                                float* __restrict__ f32out,
                                                u16* __restrict__ bf16out,
                                                u16* As, u16* Bs) {
  constexpr int NT = NDIM / 128;
  int m0 = (bidx / NT) * 128;
  int n0 = (bidx % NT) * 128;
  int tid = threadIdx.x;
  int wave = tid >> 6, lane = tid & 63;
  int wm = (wave >> 1) * 64, wn = (wave & 1) * 64;
  int quad = lane >> 4, l16 = lane & 15;
  const u16* Ab = A + (size_t)m0 * KDIM;
  const u16* Bb = Bw + (size_t)n0 * KDIM;
  f32x4 acc[4][4] = {};
  for (int k0 = 0; k0 < KDIM; k0 += 64) {
    __syncthreads();
    stage128(Ab, KDIM, k0, As, wave, lane);
    stage128(Bb, KDIM, k0, Bs, wave, lane);
    __syncthreads();
#pragma unroll
    for (int kk = 0; kk < 2; kk++) {
      int qb_ = kk * 64 + quad * 16;
      bf16x8 af[4], bfv[4];
#pragma unroll
      for (int t = 0; t < 4; t++) {
        af[t] = frag(As, wm + t * 16 + l16, qb_);
        bfv[t] = frag(Bs, wn + t * 16 + l16, qb_);
      }
#pragma unroll
      for (int tm = 0; tm < 4; tm++)
#pragma unroll
        for (int tn = 0; tn < 4; tn++)
          acc[tm][tn] = __builtin_amdgcn_mfma_f32_16x16x32_bf16(af[tm], bfv[tn], acc[tm][tn], 0, 0, 0);
    }
  }
  float bv[4];
#pragma unroll
  for (int tn = 0; tn < 4; tn++)
    bv[tn] = BIAS ? bias[n0 + wn + tn * 16 + l16] : 0.f;
#pragma unroll
  for (int tm = 0; tm < 4; tm++) {
    int mm = m0 + wm + tm * 16 + quad * 4;
#pragma unroll
    for (int tn = 0; tn < 4; tn++) {
      int nn = n0 + wn + tn * 16 + l16;
#pragma unroll
      for (int reg = 0; reg < 4; reg++) {
        float v = acc[tm][tn][reg] + bv[tn];
        if (f32out) f32out[(size_t)(mm + reg) * NDIM + nn] = v;
        if (bf16out) bf16out[(size_t)(mm + reg) * NDIM + nn] = f2bf(v);
      }
    }
  }
}

template <int KDIM, int NDIM, bool BIAS>
__global__ __launch_bounds__(256) void gemm_small_kernel(const u16* __restrict__ A,
                                                         const u16* __restrict__ Bw,
                                                         const float* __restrict__ bias,
                                                         float* __restrict__ f32out,
                                                         u16* __restrict__ bf16out) {
  __shared__ __align__(16) u16 As[128 * 64];
  __shared__ __align__(16) u16 Bs[128 * 64];
  gemm_small_body<KDIM, NDIM, BIAS>(blockIdx.x, A, Bw, bias, f32out, bf16out, As, Bs);
}

// ---------------- glob + val body ----------------
__device__ __forceinline__ void glob_val_body(int bid,
                                              const float* __restrict__ locl2,
                                              const float* __restrict__ fw,
                                              const float* __restrict__ fb,
                                              const float* __restrict__ ra,
                                              const float* __restrict__ vw,
                                              const float* __restrict__ vb,
                                              float* __restrict__ valo,
                                              float* gl) {
  int k = bid % 19;
  int b = bid / 19;
  int tid = threadIdx.x;
  float fwr[8];
#pragma unroll
  for (int m = 0; m < 8; m++) fwr[m] = fw[m];
  float fbv = fb[0], rav = ra[0];
  const float* lb = locl2 + ((size_t)(b * N_) * K_ + k) * C_;
  for (int c = tid; c < C_; c += 256) {
    float v = fbv;
#pragma unroll
    for (int m = 0; m < 8; m++) v += fwr[m] * lb[(size_t)m * K_ * C_ + c];
    gl[c] = fmaxf(v, 0.f) + rav * fminf(v, 0.f);
  }
  __syncthreads();
  int i = tid;
  const float* wr = vw + (size_t)i * C_;
  float s = vb[i];
  for (int c4 = 0; c4 < C_; c4 += 4) {
    float4 wv = *(const float4*)&wr[c4];
    float4 tv = *(const float4*)&gl[c4];
    s += wv.x * tv.x + wv.y * tv.y + wv.z * tv.z + wv.w * tv.w;
  }
  valo[(size_t)bid * CI_ + i] = s;
}

// merged: blocks 0..19 = key-projection small GEMM; blocks 20..171 = glob_val
__global__ __launch_bounds__(256) void small2_globval_kernel(const u16* __restrict__ A,
                                                             const u16* __restrict__ Bw,
                                                             const float* __restrict__ bias,
                                                             float* __restrict__ keyo,
                                                             const float* __restrict__ locl2,
                                                             const float* __restrict__ fw,
                                                             const float* __restrict__ fb,
                                                             const float* __restrict__ ra,
                                                             const float* __restrict__ vw,
                                                             const float* __restrict__ vb,
                                                             float* __restrict__ valo) {
  __shared__ __align__(16) u16 As[128 * 64];
  __shared__ __align__(16) u16 Bs[128 * 64];
  if (blockIdx.x < 20) {
    gemm_small_body<512, 256, true>(blockIdx.x, A, Bw, bias, keyo, nullptr, As, Bs);
  } else {
    glob_val_body(blockIdx.x - 20, locl2, fw, fb, ra, vw, vb, valo, (float*)As);
  }
}

// ---------------- QK2 / sbias / VO precompute ----------------
__global__ __launch_bounds__(256) void qk2vo_kernel(const float* __restrict__ keyo,
                                                    const float* __restrict__ qw,
                                                    const float* __restrict__ qb,
                                                    const float* __restrict__ valo,
                                                    const float* __restrict__ ow,
                                                    u16* __restrict__ qk2bf,
                                                    float* __restrict__ sbias,
                                                    float* __restrict__ vo) {
  __shared__ float kl[19 * 256];
  int bid = blockIdx.x, tid = threadIdx.x;
  if (bid < 64) {
    const float* ks = keyo + (size_t)bid * 19 * 256;
    for (int e = tid; e < 19 * 256; e += 256) kl[e] = ks[e];
    __syncthreads();
    if (tid < 19) {
      float s = 0.f;
      for (int i = 0; i < 256; i++) s += qb[i] * kl[tid * 256 + i];
      sbias[(size_t)bid * 19 + tid] = s;
    }
    float a0[19], a1[19];
#pragma unroll
    for (int k = 0; k < 19; k++) { a0[k] = 0.f; a1[k] = 0.f; }
    for (int i = 0; i < 256; i++) {
      float q0 = qw[(size_t)i * 512 + tid];
      float q1 = qw[(size_t)i * 512 + 256 + tid];
#pragma unroll
      for (int k = 0; k < 19; k++) {
        float kv = kl[k * 256 + i];
        a0[k] += q0 * kv;
        a1[k] += q1 * kv;
      }
    }
    u16* qo = qk2bf + (size_t)bid * 32 * 512;
#pragma unroll
    for (int k = 0; k < 19; k++) {
      qo[k * 512 + tid] = f2bf(a0[k]);
      qo[k * 512 + 256 + tid] = f2bf(a1[k]);
    }
  } else {
    int b = bid - 64;
    const float* vs = valo + (size_t)b * 19 * 256;
    for (int e = tid; e < 19 * 256; e += 256) kl[e] = vs[e];
    __syncthreads();
    float a0[19], a1[19];
#pragma unroll
    for (int k = 0; k < 19; k++) { a0[k] = 0.f; a1[k] = 0.f; }
    for (int i = 0; i < 256; i++) {
      float w0 = ow[(size_t)tid * 256 + i];
      float w1 = ow[(size_t)(tid + 256) * 256 + i];
#pragma unroll
      for (int k = 0; k < 19; k++) {
        float kv = kl[k * 256 + i];
        a0[k] += w0 * kv;
        a1[k] += w1 * kv;
      }
    }
    float* vob = vo + (size_t)b * 19 * 512;
#pragma unroll
    for (int k = 0; k < 19; k++) {
      vob[k * 512 + tid] = a0[k];
      vob[k * 512 + 256 + tid] = a1[k];
    }
  }
}

// ---------------- attention: MFMA scores + softmax + aff + BN stats ----------------
// grid 512: mt = bid&7 (128-px m-tile), n = (bid>>3)&7, b = bid>>6
__global__ __launch_bounds__(256) void attn3_kernel(const u16* __restrict__ xt,
                                                    const u16* __restrict__ qk2bf,
                                                    const float* __restrict__ sbias,
                                                    const float* __restrict__ vo,
                                                    float* __restrict__ aff,
                                                    float* __restrict__ sums,
                                                    float* __restrict__ sumsq) {
  __shared__ __align__(16) u16 As[128 * 64];
  __shared__ __align__(16) u16 Bs[32 * 64];
  __shared__ __align__(16) float aff_l[128][24];
  int bid = blockIdx.x;
  int mt = bid & 7, n = (bid >> 3) & 7, b = bid >> 6;
  int bh = n >> 2, bw = n & 3;
  int tid = threadIdx.x;
  int wave = tid >> 6, lane = tid & 63;
  int wm = wave * 32;
  int quad = lane >> 4, l16 = lane & 15;
  int hwbase = bh * 4096 + bw * 32 + mt * 512;  // mt*4 rows * 128
  const u16* Ab = xt + ((size_t)b * HW_ + hwbase) * C_;
  const u16* Bb = qk2bf + (size_t)(b * 8 + n) * 32 * 512;
  f32x4 acc[2][2] = {};
  int rsub = lane >> 3;
  int swz = ((lane & 7) ^ rsub) << 3;
  for (int k0 = 0; k0 < C_; k0 += 64) {
    __syncthreads();
#pragma unroll
    for (int i = 0; i < 4; i++) {
      int rb = wave * 8 + i * 32;
      int r = rb + rsub;
      gload16(Ab + (size_t)((r >> 5) * 128 + (r & 31)) * C_ + k0 + swz, As + rb * 64);
    }
    stage32(Bb, 512, k0, Bs, wave, lane);
    __syncthreads();
#pragma unroll
    for (int kk = 0; kk < 2; kk++) {
      int qb_ = kk * 64 + quad * 16;
      bf16x8 af2[2], bfv[2];
#pragma unroll
      for (int t = 0; t < 2; t++) {
        af2[t] = frag(As, wm + t * 16 + l16, qb_);
        bfv[t] = frag(Bs, t * 16 + l16, qb_);
      }
#pragma unroll
      for (int tm = 0; tm < 2; tm++)
#pragma unroll
        for (int tn = 0; tn < 2; tn++)
          acc[tm][tn] = __builtin_amdgcn_mfma_f32_16x16x32_bf16(af2[tm], bfv[tn], acc[tm][tn], 0, 0, 0);
    }
  }
  // softmax over k (19 classes spread across l16 in 2 n-tiles)
  const float* sb = sbias + (size_t)(b * 8 + n) * 19;
  float sb0 = sb[l16];
  float sb1 = (l16 < 3) ? sb[16 + l16] : 0.f;
#pragma unroll
  for (int tm = 0; tm < 2; tm++)
#pragma unroll
    for (int reg = 0; reg < 4; reg++) {
      float v0 = acc[tm][0][reg] + sb0;
      float v1 = (l16 < 3) ? (acc[tm][1][reg] + sb1) : -1e30f;
      float mx = fmaxf(v0, v1);
#pragma unroll
      for (int o = 8; o > 0; o >>= 1) mx = fmaxf(mx, __shfl_xor(mx, o, 16));
      float e0 = __expf(v0 - mx);
      float e1 = (l16 < 3) ? __expf(v1 - mx) : 0.f;
      float s = e0 + e1;
#pragma unroll
      for (int o = 8; o > 0; o >>= 1) s += __shfl_xor(s, o, 16);
      float inv = 1.f / s;
      int rl = wm + tm * 16 + quad * 4 + reg;
      aff_l[rl][l16] = e0 * inv;
      if (l16 < 3) aff_l[rl][16 + l16] = e1 * inv;
    }
  __syncthreads();
  // write aff (fp32) [bin][k][1024 px]
  float* ab = aff + ((size_t)(b * 8 + n) * 19) * 1024 + mt * 128;
  for (int e = tid; e < 19 * 128; e += 256) {
    int k = e >> 7, px = e & 127;
    ab[(size_t)k * 1024 + px] = aff_l[px][k];
  }
  // BN stats: y = aff . VO for this block's 128 px, all 512 c
  const float* vob = vo + (size_t)b * 19 * 512;
  float v0r[19], v1r[19];
#pragma unroll
  for (int k = 0; k < 19; k++) {
    v0r[k] = vob[k * 512 + tid];
    v1r[k] = vob[k * 512 + 256 + tid];
  }
  float s0 = 0.f, q0 = 0.f, s1 = 0.f, q1 = 0.f;
  for (int px = 0; px < 128; px++) {
    const float4* ar4 = (const float4*)aff_l[px];
    float4 a0 = ar4[0], a1 = ar4[1], a2 = ar4[2], a3 = ar4[3], a4 = ar4[4];
    float y0 = a0.x * v0r[0] + a0.y * v0r[1] + a0.z * v0r[2] + a0.w * v0r[3]
             + a1.x * v0r[4] + a1.y * v0r[5] + a1.z * v0r[6] + a1.w * v0r[7]
             + a2.x * v0r[8] + a2.y * v0r[9] + a2.z * v0r[10] + a2.w * v0r[11]
             + a3.x * v0r[12] + a3.y * v0r[13] + a3.z * v0r[14] + a3.w * v0r[15]
             + a4.x * v0r[16] + a4.y * v0r[17] + a4.z * v0r[18];
    float y1 = a0.x * v1r[0] + a0.y * v1r[1] + a0.z * v1r[2] + a0.w * v1r[3]
             + a1.x * v1r[4] + a1.y * v1r[5] + a1.z * v1r[6] + a1.w * v1r[7]
             + a2.x * v1r[8] + a2.y * v1r[9] + a2.z * v1r[10] + a2.w * v1r[11]
             + a3.x * v1r[12] + a3.y * v1r[13] + a3.z * v1r[14] + a3.w * v1r[15]
             + a4.x * v1r[16] + a4.y * v1r[17] + a4.z * v1r[18];
    s0 += y0; q0 += y0 * y0;
    s1 += y1; q1 += y1 * y1;
  }
  atomicAdd(&sums[tid], s0);
  atomicAdd(&sumsq[tid], q0);
  atomicAdd(&sums[256 + tid], s1);
  atomicAdd(&sumsq[256 + tid], q1);
}

// ---------------- final: y = aff.VO, BN(inline) + PReLU + residual ----------------
// grid 512: cq = bid&7 (64-c chunk); win = bid>>3: b = win>>3, hw0 = (win&7)*1024
// thread owns 4 consecutive px (float4 I/O, 1KB/wave-instr); vo chunk + BN in LDS
__global__ __launch_bounds__(256) void final_kernel(const float* __restrict__ x,
                                                    const float* __restrict__ aff,
                                                    const float* __restrict__ vo,
                                                    const float* __restrict__ sums,
                                                    const float* __restrict__ sumsq,
                                                    const float* __restrict__ gamma,
                                                    const float* __restrict__ beta,
                                                    const float* __restrict__ oa,
                                                    float* __restrict__ out) {
  __shared__ float vol[19][64];
  __shared__ float scl[64], shl[64], oal[64];
  int bid = blockIdx.x;
  int cq = bid & 7;
  int win = bid >> 3;
  int b = win >> 3;
  int hw0 = (win & 7) * 1024;
  int tid = threadIdx.x;
  int c0 = cq * 64;
  const float* vob = vo + (size_t)b * 19 * 512;
  for (int e = tid; e < 19 * 64; e += 256) {
    int k = e >> 6, cc = e & 63;
    vol[k][cc] = vob[k * 512 + c0 + cc];
  }
  if (tid < 64) {
    int c = c0 + tid;
    const float inv_cnt = 1.f / 65536.f;
    float mu = sums[c] * inv_cnt;
    float var = sumsq[c] * inv_cnt - mu * mu;
    float iv = rsqrtf(var + 1e-5f);
    float sc = gamma[c] * iv;
    scl[tid] = sc;
    shl[tid] = beta[c] - mu * sc;
    oal[tid] = oa[c];
  }
  __syncthreads();
  int hw = hw0 + tid * 4;
  int h = hw >> 7, w = hw & 127;
  int n = (h >> 5) * 4 + (w >> 5);
  int p = ((h & 31) << 5) + (w & 31);
  const float* ab = aff + ((size_t)(b * 8 + n) * 19) * 1024 + p;
  float4 af[19];
#pragma unroll
  for (int k = 0; k < 19; k++) af[k] = *(const float4*)&ab[(size_t)k * 1024];
  size_t base = (size_t)b * C_ * HW_ + (size_t)c0 * HW_ + hw;
  for (int c = 0; c < 64; c++) {
    float4 y;
    y.x = 0.f; y.y = 0.f; y.z = 0.f; y.w = 0.f;
#pragma unroll
    for (int k = 0; k < 19; k++) {
      float v = vol[k][c];
      y.x += af[k].x * v; y.y += af[k].y * v; y.z += af[k].z * v; y.w += af[k].w * v;
    }
    float sc = scl[c], sh = shl[c], a = oal[c];
    size_t o = base + (size_t)c * HW_;
    float4 xv = *(const float4*)&x[o];
    float4 r;
    float t;
    t = y.x * sc + sh; r.x = xv.x + fmaxf(t, 0.f) + a * fminf(t, 0.f);
    t = y.y * sc + sh; r.y = xv.y + fmaxf(t, 0.f) + a * fminf(t, 0.f);
    t = y.z * sc + sh; r.z = xv.z + fmaxf(t, 0.f) + a * fminf(t, 0.f);
    t = y.w * sc + sh; r.w = xv.w + fmaxf(t, 0.f) + a * fminf(t, 0.f);
    *(float4*)&out[o] = r;
  }
}

extern "C" void kernel_launch(void* const* d_in, const int* in_sizes, int n_in,
                              void* d_out, int out_size, void* d_ws, size_t ws_size,
                              hipStream_t stream) {
  const float* x     = (const float*)d_in[0];
  const float* camw  = (const float*)d_in[1];
  const float* camb  = (const float*)d_in[2];
  const float* gw1   = (const float*)d_in[3];
  const float* ga    = (const float*)d_in[4];
  const float* gw2   = (const float*)d_in[5];
  const float* fw    = (const float*)d_in[6];
  const float* fb    = (const float*)d_in[7];
  const float* ra    = (const float*)d_in[8];
  const float* qw    = (const float*)d_in[9];
  const float* qb    = (const float*)d_in[10];
  const float* kw    = (const float*)d_in[11];
  const float* kb    = (const float*)d_in[12];
  const float* vw    = (const float*)d_in[13];
  const float* vb    = (const float*)d_in[14];
  const float* ow    = (const float*)d_in[15];
  const float* gamma = (const float*)d_in[16];
  const float* beta  = (const float*)d_in[17];
  const float* oa    = (const float*)d_in[18];
  float* out = (float*)d_out;
  float* ws = (float*)d_ws;

  // ---- workspace layout (float units) ----
  float* cam    = ws;                          // 1,245,184
  float* bconf  = cam + 1245184;               // 2,048
  float* pconf  = bconf + 2048;                // 1,245,184
  float* aff    = pconf + 1245184;             // 1,245,184
  float* locl2f = aff + 1245184;               // 655,360
  float* keyo   = locl2f + 655360;             // 327,680
  float* valo   = keyo + 327680;               // 38,912
  float* sums   = valo + 38912;                // 512
  float* sumsq  = sums + 512;                  // 512
  float* sbias  = sumsq + 512;                 // 1,216
  float* vo     = sbias + 1216;                // 77,824
  float* part   = vo + 77824;                  // 2,490,368
  u16* kwbf   = (u16*)(part + 2490368);        // 131,072
  u16* gw2bf  = kwbf + 131072;                 // 262,144
  u16* camwbf = gw2bf + 262144;                // 16,384
  u16* tbuf   = camwbf + 16384;                // 655,360 (1280x512, rows 1216+ zeroed)
  u16* l2bf   = tbuf + 655360;                 // 655,360
  u16* qk2bf  = l2bf + 655360;                 // 1,048,576 (64 bins x 32 x 512)
  u16* xt     = qk2bf + 1048576;               // 33,554,432 (64 MB)

  xpose_prep_kernel<<<8609, 256, 0, stream>>>(x, xt, kw, gw2, camw,
                                              kwbf, gw2bf, camwbf,
                                              sums, (float*)(tbuf + 1216 * 512));
  gemm_cam_kernel<<<dim3(64, 8), 256, 0, stream>>>(xt, camwbf, camb, cam);
  softcls_kernel<<<1216, 256, 0, stream>>>(cam, bconf, pconf);
  local_part_kernel<<<512, 256, 0, stream>>>(xt, pconf, part);
  t_kernel<<<304, 256, 0, stream>>>(part, bconf, gw1, ga, tbuf);
  gemm_small_kernel<512, 512, false>
      <<<40, 256, 0, stream>>>(tbuf, gw2bf, nullptr, locl2f, l2bf);
  small2_globval_kernel<<<172, 256, 0, stream>>>(l2bf, kwbf, kb, keyo,
                                                 locl2f, fw, fb, ra, vw, vb, valo);
  qk2vo_kernel<<<72, 256, 0, stream>>>(keyo, qw, qb, valo, ow, qk2bf, sbias, vo);
  attn3_kernel<<<512, 256, 0, stream>>>(xt, qk2bf, sbias, vo, aff, sums, sumsq);
  final_kernel<<<512, 256, 0, stream>>>(x, aff, vo, sums, sumsq, gamma, beta, oa, out);
}